// Round 7
// baseline (582.217 us; speedup 1.0000x reference)
//
#include <hip/hip_runtime.h>

#define N_ROWS 65536
#define DIM 64
#define KCB 1024
#define Q_ELEMS 4194304   // 64*64*32*32
#define RPB 128           // rows per block
#define KQ 256            // codewords per wave (K-quarter)
#define TILE 32           // codewords per LDS tile (32 KB total -> 4 blocks/CU)
#define NTILES 8          // KQ / TILE

// ws layout (bytes): [0,4096) float wn2[1024]; [4096,6144) float partial[512]

// Bit-exact replica of numpy's pairwise sum of squares for 64 fp32 values.
__device__ __forceinline__ float np_pairwise_sumsq64(const float* v) {
#pragma clang fp contract(off)
    float r[8];
#pragma unroll
    for (int j = 0; j < 8; ++j) r[j] = v[j] * v[j];
#pragma unroll
    for (int i = 8; i < 64; i += 8) {
#pragma unroll
        for (int j = 0; j < 8; ++j) {
            float s = v[i + j] * v[i + j];
            r[j] = r[j] + s;
        }
    }
    return ((r[0] + r[1]) + (r[2] + r[3])) + ((r[4] + r[5]) + (r[6] + r[7]));
}

// 16 blocks x 64 threads: coalesced global loads, padded-LDS transpose,
// conflict-free per-codeword reads.
__global__ __launch_bounds__(64) void wnorm_kernel(const float* __restrict__ w,
                                                   float* __restrict__ wn2) {
    __shared__ float tile[64][65];
    const int t = threadIdx.x;
    const size_t base = (size_t)blockIdx.x * 64 * DIM;
#pragma unroll 4
    for (int i = 0; i < 64; ++i)
        tile[i][t] = w[base + (size_t)i * DIM + t];   // coalesced 256B/inst
    __syncthreads();
    float v[DIM];
#pragma unroll
    for (int d = 0; d < DIM; ++d) v[d] = tile[t][d];  // stride 65 -> no conflicts
    wn2[blockIdx.x * 64 + t] = np_pairwise_sumsq64(v);
}

__global__ __launch_bounds__(256, 4) void vq_kernel(const float* __restrict__ x,
                                                    const float* __restrict__ w,
                                                    const float* __restrict__ wn2,
                                                    float* __restrict__ out,
                                                    float* __restrict__ partial) {
    __shared__ float wtile[4][TILE * DIM];   // 32 KB; recycled for reductions at the end

    const int t = threadIdx.x;
    const int lane = t & 63;
    const int wv = t >> 6;                   // 4 waves, each owns a K-quarter
    const int rowbase = blockIdx.x * RPB;
    const int r0 = rowbase + lane;           // this thread's two rows
    const int r1 = r0 + 64;

    // x rows -> 128 VGPRs
    float xr0[DIM], xr1[DIM];
    const float4* xv0 = (const float4*)(x + (size_t)r0 * DIM);
    const float4* xv1 = (const float4*)(x + (size_t)r1 * DIM);
#pragma unroll
    for (int i = 0; i < 16; ++i) {
        float4 a = xv0[i];
        xr0[4 * i + 0] = a.x; xr0[4 * i + 1] = a.y; xr0[4 * i + 2] = a.z; xr0[4 * i + 3] = a.w;
        float4 b = xv1[i];
        xr1[4 * i + 0] = b.x; xr1[4 * i + 1] = b.y; xr1[4 * i + 2] = b.z; xr1[4 * i + 3] = b.w;
    }
    const float S0 = np_pairwise_sumsq64(xr0);
    const float S1 = np_pairwise_sumsq64(xr1);

    const int kbase = wv * KQ;               // this wave's K-quarter
    float best0 = 3.4e38f, best1 = 3.4e38f;
    int bi0 = kbase, bi1 = kbase;

    for (int tile = 0; tile < NTILES; ++tile) {
        // stage 32 codewords (8 KB) into this wave's private LDS region
        const float* gsrc = w + (size_t)(kbase + tile * TILE) * DIM;
        float* ldst = &wtile[wv][0];
#pragma unroll
        for (int j = 0; j < 8; ++j) {
            float4 v = *(const float4*)(gsrc + j * 256 + lane * 4);
            *(float4*)(ldst + j * 256 + lane * 4) = v;
        }
        // same-wave LDS RAW -> compiler-inserted lgkmcnt; no barrier needed

        for (int c = 0; c < TILE; c += 4) {
            const float* w0 = ldst + c * DIM;
            float a00 = 0.f, a01 = 0.f, a02 = 0.f, a03 = 0.f;
            float a10 = 0.f, a11 = 0.f, a12 = 0.f, a13 = 0.f;
#pragma unroll
            for (int d = 0; d < DIM; d += 4) {
                float4 u0 = *(const float4*)(w0 + 0 * DIM + d);
                float4 u1 = *(const float4*)(w0 + 1 * DIM + d);
                float4 u2 = *(const float4*)(w0 + 2 * DIM + d);
                float4 u3 = *(const float4*)(w0 + 3 * DIM + d);
                float p0 = xr0[d], p1 = xr0[d + 1], p2 = xr0[d + 2], p3 = xr0[d + 3];
                float q0 = xr1[d], q1 = xr1[d + 1], q2 = xr1[d + 2], q3 = xr1[d + 3];
                a00 = __builtin_fmaf(p0, u0.x, a00); a00 = __builtin_fmaf(p1, u0.y, a00);
                a00 = __builtin_fmaf(p2, u0.z, a00); a00 = __builtin_fmaf(p3, u0.w, a00);
                a01 = __builtin_fmaf(p0, u1.x, a01); a01 = __builtin_fmaf(p1, u1.y, a01);
                a01 = __builtin_fmaf(p2, u1.z, a01); a01 = __builtin_fmaf(p3, u1.w, a01);
                a02 = __builtin_fmaf(p0, u2.x, a02); a02 = __builtin_fmaf(p1, u2.y, a02);
                a02 = __builtin_fmaf(p2, u2.z, a02); a02 = __builtin_fmaf(p3, u2.w, a02);
                a03 = __builtin_fmaf(p0, u3.x, a03); a03 = __builtin_fmaf(p1, u3.y, a03);
                a03 = __builtin_fmaf(p2, u3.z, a03); a03 = __builtin_fmaf(p3, u3.w, a03);
                a10 = __builtin_fmaf(q0, u0.x, a10); a10 = __builtin_fmaf(q1, u0.y, a10);
                a10 = __builtin_fmaf(q2, u0.z, a10); a10 = __builtin_fmaf(q3, u0.w, a10);
                a11 = __builtin_fmaf(q0, u1.x, a11); a11 = __builtin_fmaf(q1, u1.y, a11);
                a11 = __builtin_fmaf(q2, u1.z, a11); a11 = __builtin_fmaf(q3, u1.w, a11);
                a12 = __builtin_fmaf(q0, u2.x, a12); a12 = __builtin_fmaf(q1, u2.y, a12);
                a12 = __builtin_fmaf(q2, u2.z, a12); a12 = __builtin_fmaf(q3, u2.w, a12);
                a13 = __builtin_fmaf(q0, u3.x, a13); a13 = __builtin_fmaf(q1, u3.y, a13);
                a13 = __builtin_fmaf(q2, u3.z, a13); a13 = __builtin_fmaf(q3, u3.w, a13);
            }
            const int k = kbase + tile * TILE + c;
            float wnA = wn2[k + 0], wnB = wn2[k + 1], wnC = wn2[k + 2], wnD = wn2[k + 3];
            float d00 = (S0 + wnA) - 2.0f * a00;
            float d01 = (S0 + wnB) - 2.0f * a01;
            float d02 = (S0 + wnC) - 2.0f * a02;
            float d03 = (S0 + wnD) - 2.0f * a03;
            if (d00 < best0) { best0 = d00; bi0 = k + 0; }
            if (d01 < best0) { best0 = d01; bi0 = k + 1; }
            if (d02 < best0) { best0 = d02; bi0 = k + 2; }
            if (d03 < best0) { best0 = d03; bi0 = k + 3; }
            float d10 = (S1 + wnA) - 2.0f * a10;
            float d11 = (S1 + wnB) - 2.0f * a11;
            float d12 = (S1 + wnC) - 2.0f * a12;
            float d13 = (S1 + wnD) - 2.0f * a13;
            if (d10 < best1) { best1 = d10; bi1 = k + 0; }
            if (d11 < best1) { best1 = d11; bi1 = k + 1; }
            if (d12 < best1) { best1 = d12; bi1 = k + 2; }
            if (d13 < best1) { best1 = d13; bi1 = k + 3; }
        }
    }

    // recycle wtile for the cross-quarter argmin + loss reduction
    __syncthreads();
    float* cbd = (float*)&wtile[0][0];                    // [4][128]
    int*   cbk = (int*)((char*)&wtile[0][0] + 2048);      // [4][128]
    float* red = (float*)((char*)&wtile[0][0] + 4096);    // [4]
    cbd[wv * 128 + lane]      = best0;  cbk[wv * 128 + lane]      = bi0;
    cbd[wv * 128 + 64 + lane] = best1;  cbk[wv * 128 + 64 + lane] = bi1;
    __syncthreads();

    float lsum = 0.f;
    if (t < 128) {
        const int rb = t;                                 // row-in-block
        // combine quarters ascending: strict < == global first-occurrence argmin
        float bd = cbd[0 * 128 + rb]; int bk = cbk[0 * 128 + rb];
#pragma unroll
        for (int q = 1; q < 4; ++q) {
            float dq = cbd[q * 128 + rb]; int kq = cbk[q * 128 + rb];
            if (dq < bd) { bd = dq; bk = kq; }
        }
        // thread t holds row rowbase+t in xr0 (wave0) / xr1 (wave1)
        float xcur[DIM];
        if (wv == 0) {
#pragma unroll
            for (int d = 0; d < DIM; ++d) xcur[d] = xr0[d];
        } else {
#pragma unroll
            for (int d = 0; d < DIM; ++d) xcur[d] = xr1[d];
        }
        const int n = rowbase + rb;
        const int b = n >> 10;               // H*W = 1024
        const int hw = n & 1023;
        float* outq = out + 1 + (size_t)b * 65536 + hw;
        const float4* wr4 = (const float4*)(w + (size_t)bk * DIM);
#pragma unroll
        for (int i = 0; i < 16; ++i) {
            float4 u = wr4[i];
            float d0 = u.x - xcur[4 * i + 0];
            float d1 = u.y - xcur[4 * i + 1];
            float d2 = u.z - xcur[4 * i + 2];
            float d3 = u.w - xcur[4 * i + 3];
            lsum += d0 * d0; lsum += d1 * d1; lsum += d2 * d2; lsum += d3 * d3;
            outq[(size_t)(4 * i + 0) * 1024] = xcur[4 * i + 0] + d0;
            outq[(size_t)(4 * i + 1) * 1024] = xcur[4 * i + 1] + d1;
            outq[(size_t)(4 * i + 2) * 1024] = xcur[4 * i + 2] + d2;
            outq[(size_t)(4 * i + 3) * 1024] = xcur[4 * i + 3] + d3;
        }
        out[1 + Q_ELEMS + n] = (float)bk;
    }
#pragma unroll
    for (int off = 32; off > 0; off >>= 1) lsum += __shfl_down(lsum, off, 64);
    if (lane == 0) red[wv] = lsum;
    __syncthreads();
    if (t == 0) partial[blockIdx.x] = (red[0] + red[1]) + (red[2] + red[3]);
}

__global__ void finish_kernel(const float* __restrict__ partial, float* __restrict__ out) {
    float v = partial[threadIdx.x] + partial[threadIdx.x + 256];
#pragma unroll
    for (int off = 32; off > 0; off >>= 1) v += __shfl_down(v, off, 64);
    __shared__ float red[4];
    const int lane = threadIdx.x & 63;
    const int wv = threadIdx.x >> 6;
    if (lane == 0) red[wv] = v;
    __syncthreads();
    if (threadIdx.x == 0) {
        float total = (red[0] + red[1]) + (red[2] + red[3]);
        out[0] = total * (2.0f / (float)(N_ROWS * DIM));
    }
}

extern "C" void kernel_launch(void* const* d_in, const int* in_sizes, int n_in,
                              void* d_out, int out_size, void* d_ws, size_t ws_size,
                              hipStream_t stream) {
    const float* x = (const float*)d_in[0];
    const float* w = (const float*)d_in[1];
    float* out = (float*)d_out;

    char* ws = (char*)d_ws;
    float* wn2 = (float*)(ws + 0);
    float* partial = (float*)(ws + 4096);

    wnorm_kernel<<<KCB / 64, 64, 0, stream>>>(w, wn2);
    vq_kernel<<<N_ROWS / RPB, 256, 0, stream>>>(x, w, wn2, out, partial);
    finish_kernel<<<1, 256, 0, stream>>>(partial, out);
}

// Round 8
// 209.661 us; speedup vs baseline: 2.7769x; 2.7769x over previous
//
#include <hip/hip_runtime.h>

#define N_ROWS 65536
#define DIM 64
#define KCB 1024
#define Q_ELEMS 4194304   // 64*64*32*32
#define RPB 128           // rows per block
#define KQ 256            // codewords per wave (K-quarter)
#define TILE 32           // codewords per LDS tile (4 waves x 8KB = 32KB/block)
#define NTILES 8          // KQ / TILE

// ws layout (bytes): [0,4096) float wn2[1024]; [4096,6144) float partial[512]

// Bit-exact replica of numpy's pairwise sum of squares for 64 fp32 values.
__device__ __forceinline__ float np_pairwise_sumsq64(const float* v) {
#pragma clang fp contract(off)
    float r[8];
#pragma unroll
    for (int j = 0; j < 8; ++j) r[j] = v[j] * v[j];
#pragma unroll
    for (int i = 8; i < 64; i += 8) {
#pragma unroll
        for (int j = 0; j < 8; ++j) {
            float s = v[i + j] * v[i + j];
            r[j] = r[j] + s;
        }
    }
    return ((r[0] + r[1]) + (r[2] + r[3])) + ((r[4] + r[5]) + (r[6] + r[7]));
}

__global__ __launch_bounds__(64) void wnorm_kernel(const float* __restrict__ w,
                                                   float* __restrict__ wn2) {
    __shared__ float tile[64][65];
    const int t = threadIdx.x;
    const size_t base = (size_t)blockIdx.x * 64 * DIM;
#pragma unroll 4
    for (int i = 0; i < 64; ++i)
        tile[i][t] = w[base + (size_t)i * DIM + t];   // coalesced
    __syncthreads();
    float v[DIM];
#pragma unroll
    for (int d = 0; d < DIM; ++d) v[d] = tile[t][d];  // stride 65 -> conflict-free
    wn2[blockIdx.x * 64 + t] = np_pairwise_sumsq64(v);
}

// NOTE __launch_bounds__(256, 2): empirically (R5/R6/R7) the backend budgets
// VGPRs ~= 256/min_waves_per_EU; this kernel's live set (two x rows) needs 128,
// so min_waves_per_EU must be 2. Occupancy beyond that comes from HW (128 VGPR
// -> 4 waves/SIMD) once LDS fits (32KB -> 4+ blocks/CU).
__global__ __launch_bounds__(256, 2) void vq_kernel(const float* __restrict__ x,
                                                    const float* __restrict__ w,
                                                    const float* __restrict__ wn2,
                                                    float* __restrict__ out,
                                                    float* __restrict__ partial) {
    __shared__ float wtile[4][TILE * DIM];   // 32 KB; recycled for reductions

    const int t = threadIdx.x;
    const int lane = t & 63;
    const int wv = t >> 6;                   // 4 waves, each owns a K-quarter
    const int rowbase = blockIdx.x * RPB;
    const int r0 = rowbase + lane;           // this thread's two rows
    const int r1 = r0 + 64;

    // x rows -> 128 VGPRs
    float xr0[DIM], xr1[DIM];
    const float4* xv0 = (const float4*)(x + (size_t)r0 * DIM);
    const float4* xv1 = (const float4*)(x + (size_t)r1 * DIM);
#pragma unroll
    for (int i = 0; i < 16; ++i) {
        float4 a = xv0[i];
        xr0[4 * i + 0] = a.x; xr0[4 * i + 1] = a.y; xr0[4 * i + 2] = a.z; xr0[4 * i + 3] = a.w;
        float4 b = xv1[i];
        xr1[4 * i + 0] = b.x; xr1[4 * i + 1] = b.y; xr1[4 * i + 2] = b.z; xr1[4 * i + 3] = b.w;
    }
    const float S0 = np_pairwise_sumsq64(xr0);
    const float S1 = np_pairwise_sumsq64(xr1);

    const int kbase = wv * KQ;               // this wave's K-quarter
    float best0 = 3.4e38f, best1 = 3.4e38f;
    int bi0 = kbase, bi1 = kbase;

    for (int tile = 0; tile < NTILES; ++tile) {
        // stage 32 codewords (8 KB) into this wave's private LDS region
        const float* gsrc = w + (size_t)(kbase + tile * TILE) * DIM;
        float* ldst = &wtile[wv][0];
#pragma unroll
        for (int j = 0; j < 8; ++j) {
            float4 v = *(const float4*)(gsrc + j * 256 + lane * 4);
            *(float4*)(ldst + j * 256 + lane * 4) = v;
        }
        // same-wave LDS RAW -> compiler-inserted lgkmcnt; no barrier needed

        for (int c = 0; c < TILE; c += 4) {
            const float* w0 = ldst + c * DIM;
            float a00 = 0.f, a01 = 0.f, a02 = 0.f, a03 = 0.f;
            float a10 = 0.f, a11 = 0.f, a12 = 0.f, a13 = 0.f;
#pragma unroll
            for (int d = 0; d < DIM; d += 4) {
                float4 u0 = *(const float4*)(w0 + 0 * DIM + d);
                float4 u1 = *(const float4*)(w0 + 1 * DIM + d);
                float4 u2 = *(const float4*)(w0 + 2 * DIM + d);
                float4 u3 = *(const float4*)(w0 + 3 * DIM + d);
                float p0 = xr0[d], p1 = xr0[d + 1], p2 = xr0[d + 2], p3 = xr0[d + 3];
                float q0 = xr1[d], q1 = xr1[d + 1], q2 = xr1[d + 2], q3 = xr1[d + 3];
                a00 = __builtin_fmaf(p0, u0.x, a00); a00 = __builtin_fmaf(p1, u0.y, a00);
                a00 = __builtin_fmaf(p2, u0.z, a00); a00 = __builtin_fmaf(p3, u0.w, a00);
                a01 = __builtin_fmaf(p0, u1.x, a01); a01 = __builtin_fmaf(p1, u1.y, a01);
                a01 = __builtin_fmaf(p2, u1.z, a01); a01 = __builtin_fmaf(p3, u1.w, a01);
                a02 = __builtin_fmaf(p0, u2.x, a02); a02 = __builtin_fmaf(p1, u2.y, a02);
                a02 = __builtin_fmaf(p2, u2.z, a02); a02 = __builtin_fmaf(p3, u2.w, a02);
                a03 = __builtin_fmaf(p0, u3.x, a03); a03 = __builtin_fmaf(p1, u3.y, a03);
                a03 = __builtin_fmaf(p2, u3.z, a03); a03 = __builtin_fmaf(p3, u3.w, a03);
                a10 = __builtin_fmaf(q0, u0.x, a10); a10 = __builtin_fmaf(q1, u0.y, a10);
                a10 = __builtin_fmaf(q2, u0.z, a10); a10 = __builtin_fmaf(q3, u0.w, a10);
                a11 = __builtin_fmaf(q0, u1.x, a11); a11 = __builtin_fmaf(q1, u1.y, a11);
                a11 = __builtin_fmaf(q2, u1.z, a11); a11 = __builtin_fmaf(q3, u1.w, a11);
                a12 = __builtin_fmaf(q0, u2.x, a12); a12 = __builtin_fmaf(q1, u2.y, a12);
                a12 = __builtin_fmaf(q2, u2.z, a12); a12 = __builtin_fmaf(q3, u2.w, a12);
                a13 = __builtin_fmaf(q0, u3.x, a13); a13 = __builtin_fmaf(q1, u3.y, a13);
                a13 = __builtin_fmaf(q2, u3.z, a13); a13 = __builtin_fmaf(q3, u3.w, a13);
            }
            const int k = kbase + tile * TILE + c;
            float wnA = wn2[k + 0], wnB = wn2[k + 1], wnC = wn2[k + 2], wnD = wn2[k + 3];
            float d00 = (S0 + wnA) - 2.0f * a00;
            float d01 = (S0 + wnB) - 2.0f * a01;
            float d02 = (S0 + wnC) - 2.0f * a02;
            float d03 = (S0 + wnD) - 2.0f * a03;
            if (d00 < best0) { best0 = d00; bi0 = k + 0; }
            if (d01 < best0) { best0 = d01; bi0 = k + 1; }
            if (d02 < best0) { best0 = d02; bi0 = k + 2; }
            if (d03 < best0) { best0 = d03; bi0 = k + 3; }
            float d10 = (S1 + wnA) - 2.0f * a10;
            float d11 = (S1 + wnB) - 2.0f * a11;
            float d12 = (S1 + wnC) - 2.0f * a12;
            float d13 = (S1 + wnD) - 2.0f * a13;
            if (d10 < best1) { best1 = d10; bi1 = k + 0; }
            if (d11 < best1) { best1 = d11; bi1 = k + 1; }
            if (d12 < best1) { best1 = d12; bi1 = k + 2; }
            if (d13 < best1) { best1 = d13; bi1 = k + 3; }
        }
    }

    // recycle wtile for the cross-quarter argmin + loss reduction
    __syncthreads();
    float* cbd = (float*)&wtile[0][0];                    // [4][128]
    int*   cbk = (int*)((char*)&wtile[0][0] + 2048);      // [4][128]
    float* red = (float*)((char*)&wtile[0][0] + 4096);    // [4]
    cbd[wv * 128 + lane]      = best0;  cbk[wv * 128 + lane]      = bi0;
    cbd[wv * 128 + 64 + lane] = best1;  cbk[wv * 128 + 64 + lane] = bi1;
    __syncthreads();

    float lsum = 0.f;
    if (t < 128) {
        const int rb = t;                                 // row-in-block
        float bd = cbd[0 * 128 + rb]; int bk = cbk[0 * 128 + rb];
#pragma unroll
        for (int q = 1; q < 4; ++q) {
            float dq = cbd[q * 128 + rb]; int kq = cbk[q * 128 + rb];
            if (dq < bd) { bd = dq; bk = kq; }
        }
        float xcur[DIM];
        if (wv == 0) {
#pragma unroll
            for (int d = 0; d < DIM; ++d) xcur[d] = xr0[d];
        } else {
#pragma unroll
            for (int d = 0; d < DIM; ++d) xcur[d] = xr1[d];
        }
        const int n = rowbase + rb;
        const int b = n >> 10;               // H*W = 1024
        const int hw = n & 1023;
        float* outq = out + 1 + (size_t)b * 65536 + hw;
        const float4* wr4 = (const float4*)(w + (size_t)bk * DIM);
#pragma unroll
        for (int i = 0; i < 16; ++i) {
            float4 u = wr4[i];
            float d0 = u.x - xcur[4 * i + 0];
            float d1 = u.y - xcur[4 * i + 1];
            float d2 = u.z - xcur[4 * i + 2];
            float d3 = u.w - xcur[4 * i + 3];
            lsum += d0 * d0; lsum += d1 * d1; lsum += d2 * d2; lsum += d3 * d3;
            outq[(size_t)(4 * i + 0) * 1024] = xcur[4 * i + 0] + d0;
            outq[(size_t)(4 * i + 1) * 1024] = xcur[4 * i + 1] + d1;
            outq[(size_t)(4 * i + 2) * 1024] = xcur[4 * i + 2] + d2;
            outq[(size_t)(4 * i + 3) * 1024] = xcur[4 * i + 3] + d3;
        }
        out[1 + Q_ELEMS + n] = (float)bk;
    }
#pragma unroll
    for (int off = 32; off > 0; off >>= 1) lsum += __shfl_down(lsum, off, 64);
    if (lane == 0) red[wv] = lsum;
    __syncthreads();
    if (t == 0) partial[blockIdx.x] = (red[0] + red[1]) + (red[2] + red[3]);
}

__global__ void finish_kernel(const float* __restrict__ partial, float* __restrict__ out) {
    float v = partial[threadIdx.x] + partial[threadIdx.x + 256];
#pragma unroll
    for (int off = 32; off > 0; off >>= 1) v += __shfl_down(v, off, 64);
    __shared__ float red[4];
    const int lane = threadIdx.x & 63;
    const int wv = threadIdx.x >> 6;
    if (lane == 0) red[wv] = v;
    __syncthreads();
    if (threadIdx.x == 0) {
        float total = (red[0] + red[1]) + (red[2] + red[3]);
        out[0] = total * (2.0f / (float)(N_ROWS * DIM));
    }
}

extern "C" void kernel_launch(void* const* d_in, const int* in_sizes, int n_in,
                              void* d_out, int out_size, void* d_ws, size_t ws_size,
                              hipStream_t stream) {
    const float* x = (const float*)d_in[0];
    const float* w = (const float*)d_in[1];
    float* out = (float*)d_out;

    char* ws = (char*)d_ws;
    float* wn2 = (float*)(ws + 0);
    float* partial = (float*)(ws + 4096);

    wnorm_kernel<<<KCB / 64, 64, 0, stream>>>(w, wn2);
    vq_kernel<<<N_ROWS / RPB, 256, 0, stream>>>(x, w, wn2, out, partial);
    finish_kernel<<<1, 256, 0, stream>>>(partial, out);
}